// Round 1
// baseline (161.461 us; speedup 1.0000x reference)
//
#include <hip/hip_runtime.h>
#include <hip/hip_fp8.h>

// Problem geometry (from reference): T=8192 rows, H=4096 cols, all f32 in.
// Outputs concatenated: [ q_dyn (T*H f32-widened fp8 values), residual_out (T*H f32) ]

static constexpr int H_DIM = 4096;

__device__ __forceinline__ unsigned char f32_to_fp8(float x) {
    __hip_fp8_e4m3 f(x);   // OCP e4m3fn, SATFINITE, RNE (HW cvt on gfx950)
    return f.__x;
}

__device__ __forceinline__ float fp8_to_f32(unsigned char b) {
    __hip_fp8_e4m3 f;
    f.__x = b;
    return (float)f;
}

// Kernel 1: one block per row. add + RMSNorm + static fp8 quant.
// Writes residual_out, fp8 bytes (or per-row inv in fallback mode), and
// contributes to global amax of |dequantized| values.
template <bool STORE_Q8>
__global__ __launch_bounds__(256) void k_rms_quant(
    const float* __restrict__ hs, const float* __restrict__ res,
    const float* __restrict__ w, const float* __restrict__ scale_p,
    float* __restrict__ resid_out, unsigned char* __restrict__ q8,
    float* __restrict__ inv_arr, unsigned int* __restrict__ amax_bits)
{
    const int row = blockIdx.x;
    const int t   = threadIdx.x;
    const size_t base = (size_t)row * H_DIM;

    float4 a[4];
    double ss = 0.0;
#pragma unroll
    for (int c = 0; c < 4; ++c) {
        const int col = c * 1024 + t * 4;
        const float4 hv = *(const float4*)(hs + base + col);
        const float4 rv = *(const float4*)(res + base + col);
        float4 av;
        av.x = hv.x + rv.x; av.y = hv.y + rv.y;
        av.z = hv.z + rv.z; av.w = hv.w + rv.w;
        a[c] = av;
        *(float4*)(resid_out + base + col) = av;
        ss += (double)av.x * (double)av.x + (double)av.y * (double)av.y
            + (double)av.z * (double)av.z + (double)av.w * (double)av.w;
    }

    // Block reduction of sum-of-squares (4 waves of 64).
    __shared__ double sred[4];
#pragma unroll
    for (int o = 32; o > 0; o >>= 1) ss += __shfl_down(ss, o, 64);
    const int lane = t & 63, wid = t >> 6;
    if (lane == 0) sred[wid] = ss;
    __syncthreads();
    if (t == 0) sred[0] = sred[0] + sred[1] + sred[2] + sred[3];
    __syncthreads();
    const double tot = sred[0];
    const float inv = (float)(1.0 / sqrt(tot / (double)H_DIM + 1e-6));
    if (!STORE_Q8 && t == 0) inv_arr[row] = inv;

    const float s = scale_p[0];
    float lmax = 0.0f;
#pragma unroll
    for (int c = 0; c < 4; ++c) {
        const int col = c * 1024 + t * 4;
        const float4 wv = *(const float4*)(w + col);
        const float4 av = a[c];
        const float q0 = (av.x * inv) * wv.x / s;
        const float q1 = (av.y * inv) * wv.y / s;
        const float q2 = (av.z * inv) * wv.z / s;
        const float q3 = (av.w * inv) * wv.w / s;
        uchar4 b;
        b.x = f32_to_fp8(q0); b.y = f32_to_fp8(q1);
        b.z = f32_to_fp8(q2); b.w = f32_to_fp8(q3);
        if (STORE_Q8) *(uchar4*)(q8 + base + col) = b;
        const float d0 = fabsf(fp8_to_f32(b.x));
        const float d1 = fabsf(fp8_to_f32(b.y));
        const float d2 = fabsf(fp8_to_f32(b.z));
        const float d3 = fabsf(fp8_to_f32(b.w));
        lmax = fmaxf(lmax, fmaxf(fmaxf(d0, d1), fmaxf(d2, d3)));
    }

    __shared__ float smax[4];
#pragma unroll
    for (int o = 32; o > 0; o >>= 1) lmax = fmaxf(lmax, __shfl_down(lmax, o, 64));
    if (lane == 0) smax[wid] = lmax;
    __syncthreads();
    if (t == 0) {
        const float bm = fmaxf(fmaxf(smax[0], smax[1]), fmaxf(smax[2], smax[3]));
        // Non-negative floats order-compare correctly as uint bit patterns.
        atomicMax(amax_bits, __float_as_uint(bm));
    }
}

// Kernel 2 (primary): re-quantize from stored fp8 bytes with the dynamic scale.
__global__ __launch_bounds__(256) void k_requant(
    const unsigned char* __restrict__ q8,
    const unsigned int* __restrict__ amax_bits,
    float* __restrict__ out, size_t n)
{
    const float amax   = __uint_as_float(*amax_bits);
    const float dscale = fmaxf(amax, 1e-12f) / 448.0f;
    size_t i = ((size_t)blockIdx.x * blockDim.x + threadIdx.x) * 8;
    const size_t stride = (size_t)gridDim.x * blockDim.x * 8;
    for (; i + 7 < n; i += stride) {
        uint2 packed = *(const uint2*)(q8 + i);
        const unsigned char* b = (const unsigned char*)&packed;
        float v[8];
#pragma unroll
        for (int j = 0; j < 8; ++j) {
            const float deq = fp8_to_f32(b[j]);
            float q = deq / dscale;                       // true f32 divide (match ref)
            q = fminf(fmaxf(q, -448.0f), 448.0f);
            v[j] = fp8_to_f32(f32_to_fp8(q));
        }
        *(float4*)(out + i)     = make_float4(v[0], v[1], v[2], v[3]);
        *(float4*)(out + i + 4) = make_float4(v[4], v[5], v[6], v[7]);
    }
}

// Kernel 2 (fallback, ws too small for fp8 intermediate): recompute the static
// quant from residual_out + per-row inv, then requantize.
__global__ __launch_bounds__(256) void k_requant_rows(
    const float* __restrict__ resid_out, const float* __restrict__ w,
    const float* __restrict__ scale_p, const float* __restrict__ inv_arr,
    const unsigned int* __restrict__ amax_bits, float* __restrict__ out)
{
    const int row = blockIdx.x;
    const int t   = threadIdx.x;
    const size_t base = (size_t)row * H_DIM;
    const float inv = inv_arr[row];
    const float s = scale_p[0];
    const float amax   = __uint_as_float(*amax_bits);
    const float dscale = fmaxf(amax, 1e-12f) / 448.0f;
#pragma unroll
    for (int c = 0; c < 4; ++c) {
        const int col = c * 1024 + t * 4;
        const float4 av = *(const float4*)(resid_out + base + col);
        const float4 wv = *(const float4*)(w + col);
        float v[4];
        const float qs[4] = { (av.x * inv) * wv.x / s, (av.y * inv) * wv.y / s,
                              (av.z * inv) * wv.z / s, (av.w * inv) * wv.w / s };
#pragma unroll
        for (int j = 0; j < 4; ++j) {
            const float deq = fp8_to_f32(f32_to_fp8(qs[j]));
            float q = deq / dscale;
            q = fminf(fmaxf(q, -448.0f), 448.0f);
            v[j] = fp8_to_f32(f32_to_fp8(q));
        }
        *(float4*)(out + base + col) = make_float4(v[0], v[1], v[2], v[3]);
    }
}

extern "C" void kernel_launch(void* const* d_in, const int* in_sizes, int n_in,
                              void* d_out, int out_size, void* d_ws, size_t ws_size,
                              hipStream_t stream) {
    const float* hs    = (const float*)d_in[0];
    const float* res   = (const float*)d_in[1];
    const float* w     = (const float*)d_in[2];
    const float* scale = (const float*)d_in[3];
    const int Hn = in_sizes[2];           // 4096
    const int Tn = in_sizes[0] / Hn;      // 8192
    const size_t nelem = (size_t)Tn * Hn;

    float* q_dyn_out = (float*)d_out;            // first output, flat
    float* resid_out = (float*)d_out + nelem;    // second output, flat

    unsigned int* amax_bits = (unsigned int*)d_ws;
    unsigned char* q8 = (unsigned char*)d_ws + 256;
    float* inv_arr = (float*)((unsigned char*)d_ws + 256);

    // amax slot must be re-zeroed every call (ws is poisoned 0xAA once and
    // never restored; 0xAAAAAAAA compares as a huge uint vs float bits).
    hipMemsetAsync(d_ws, 0, 256, stream);

    const bool use_q8 = ws_size >= 256 + nelem;

    if (use_q8) {
        k_rms_quant<true><<<Tn, 256, 0, stream>>>(hs, res, w, scale,
                                                  resid_out, q8, inv_arr, amax_bits);
        k_requant<<<2048, 256, 0, stream>>>(q8, amax_bits, q_dyn_out, nelem);
    } else {
        k_rms_quant<false><<<Tn, 256, 0, stream>>>(hs, res, w, scale,
                                                   resid_out, q8, inv_arr, amax_bits);
        k_requant_rows<<<Tn, 256, 0, stream>>>(resid_out, w, scale, inv_arr,
                                               amax_bits, q_dyn_out);
    }
}

// Round 2
// 127.981 us; speedup vs baseline: 1.2616x; 1.2616x over previous
//
#include <hip/hip_runtime.h>

// T=8192 rows, H=4096 cols, f32 inputs.
// Outputs concat: [ q_dyn (T*H, f32-widened fp8), residual_out (T*H, f32) ]
//
// Plan (576 MB total HBM traffic ~= 91 us roofline):
//  k1: per-row add + RMSNorm + static fp8 quant -> resid_out (128MB W),
//      q8 words (32MB W), per-block max|q| (plain store, no memset/atomic).
//  k2: reduce 8192 block-maxes (L2), dynamic requant from q8 -> q_dyn (128MB W).

typedef float v2f __attribute__((ext_vector_type(2)));

static constexpr int H_DIM = 4096;
#define FP8_MAX_F 448.0f

// HW RNE saturating f32->fp8(e4m3fn) pack, 4 elements -> one u32.
__device__ __forceinline__ unsigned int quant4(float q0, float q1, float q2, float q3) {
    unsigned int pk = 0;
    pk = __builtin_amdgcn_cvt_pk_fp8_f32(q0, q1, pk, false); // bytes 0,1
    pk = __builtin_amdgcn_cvt_pk_fp8_f32(q2, q3, pk, true);  // bytes 2,3
    return pk;
}

__device__ __forceinline__ float fp8_roundtrip1(float x) {
    unsigned int pk = __builtin_amdgcn_cvt_pk_fp8_f32(x, x, 0, false);
    v2f d = __builtin_amdgcn_cvt_pk_f32_fp8((int)pk, false);
    return d[0];
}

// --- Kernel 1: one block per row ---
__global__ __launch_bounds__(256) void k_rms_quant(
    const float* __restrict__ hs, const float* __restrict__ res,
    const float* __restrict__ w, const float* __restrict__ scale_p,
    float* __restrict__ resid_out, unsigned int* __restrict__ q8w,
    float* __restrict__ blockmax)
{
    const int row = blockIdx.x;
    const int t   = threadIdx.x;
    const size_t base  = (size_t)row * H_DIM;   // in floats
    const size_t base4 = base >> 2;             // in u32 words of q8

    float4 a[4];
    double ss = 0.0;
#pragma unroll
    for (int c = 0; c < 4; ++c) {
        const int col = c * 1024 + t * 4;
        const float4 hv = *(const float4*)(hs + base + col);
        const float4 rv = *(const float4*)(res + base + col);
        float4 av;
        av.x = hv.x + rv.x; av.y = hv.y + rv.y;
        av.z = hv.z + rv.z; av.w = hv.w + rv.w;
        a[c] = av;
        *(float4*)(resid_out + base + col) = av;
        ss += (double)av.x * (double)av.x + (double)av.y * (double)av.y
            + (double)av.z * (double)av.z + (double)av.w * (double)av.w;
    }

    // Block reduction of sum-of-squares (4 waves of 64).
    __shared__ double sred[4];
#pragma unroll
    for (int o = 32; o > 0; o >>= 1) ss += __shfl_down(ss, o, 64);
    const int lane = t & 63, wid = t >> 6;
    if (lane == 0) sred[wid] = ss;
    __syncthreads();
    if (t == 0) sred[0] = sred[0] + sred[1] + sred[2] + sred[3];
    __syncthreads();
    const float inv = (float)(1.0 / sqrt(sred[0] / (double)H_DIM + 1e-6));

    const float s = scale_p[0];
    float lmax = 0.0f;
#pragma unroll
    for (int c = 0; c < 4; ++c) {
        const int col = c * 1024 + t * 4;
        const float4 wv = *(const float4*)(w + col);
        const float4 av = a[c];
        float q0 = (av.x * inv) * wv.x / s;
        float q1 = (av.y * inv) * wv.y / s;
        float q2 = (av.z * inv) * wv.z / s;
        float q3 = (av.w * inv) * wv.w / s;
        q0 = fminf(fmaxf(q0, -FP8_MAX_F), FP8_MAX_F);
        q1 = fminf(fmaxf(q1, -FP8_MAX_F), FP8_MAX_F);
        q2 = fminf(fmaxf(q2, -FP8_MAX_F), FP8_MAX_F);
        q3 = fminf(fmaxf(q3, -FP8_MAX_F), FP8_MAX_F);
        q8w[base4 + c * 256 + t] = quant4(q0, q1, q2, q3);
        // max|deq| == roundtrip(max|q|): RNE fp8 quant is monotone & symmetric,
        // so only the pre-quant |q| max is needed here.
        lmax = fmaxf(lmax, fmaxf(fmaxf(fabsf(q0), fabsf(q1)),
                                 fmaxf(fabsf(q2), fabsf(q3))));
    }

    __shared__ float smax[4];
#pragma unroll
    for (int o = 32; o > 0; o >>= 1) lmax = fmaxf(lmax, __shfl_down(lmax, o, 64));
    if (lane == 0) smax[wid] = lmax;
    __syncthreads();
    if (t == 0)
        blockmax[row] = fmaxf(fmaxf(smax[0], smax[1]), fmaxf(smax[2], smax[3]));
}

// --- Kernel 2: reduce blockmax, then dynamic requant from fp8 bytes ---
__global__ __launch_bounds__(256) void k_requant(
    const unsigned int* __restrict__ q8w,
    const float* __restrict__ blockmax, int nblk,
    float* __restrict__ out, size_t nwords)
{
    const int t = threadIdx.x;
    const int lane = t & 63, wid = t >> 6;

    // Every block reduces the 8192-entry blockmax array (32KB, L2-resident).
    float m = 0.0f;
    for (int i = t * 4; i < nblk; i += 256 * 4) {
        const float4 v = *(const float4*)(blockmax + i);
        m = fmaxf(fmaxf(m, fmaxf(v.x, v.y)), fmaxf(v.z, v.w));
    }
#pragma unroll
    for (int o = 32; o > 0; o >>= 1) m = fmaxf(m, __shfl_down(m, o, 64));
    __shared__ float sm[4];
    if (lane == 0) sm[wid] = m;
    __syncthreads();
    const float amax_q = fmaxf(fmaxf(sm[0], sm[1]), fmaxf(sm[2], sm[3]));
    const float amax   = fp8_roundtrip1(amax_q);          // = max|dequantized|
    const float dscale = fmaxf(amax, 1e-12f) / FP8_MAX_F;

    size_t i = ((size_t)blockIdx.x * 256 + t) * 2;        // in u32 words
    const size_t stride = (size_t)gridDim.x * 256 * 2;
    for (; i + 1 < nwords; i += stride) {
        const uint2 pw = *(const uint2*)(q8w + i);
#pragma unroll
        for (int j = 0; j < 2; ++j) {
            const unsigned int wv = j ? pw.y : pw.x;
            const v2f lo = __builtin_amdgcn_cvt_pk_f32_fp8((int)wv, false);
            const v2f hi = __builtin_amdgcn_cvt_pk_f32_fp8((int)wv, true);
            float q0 = lo[0] / dscale, q1 = lo[1] / dscale;
            float q2 = hi[0] / dscale, q3 = hi[1] / dscale;
            q0 = fminf(fmaxf(q0, -FP8_MAX_F), FP8_MAX_F);
            q1 = fminf(fmaxf(q1, -FP8_MAX_F), FP8_MAX_F);
            q2 = fminf(fmaxf(q2, -FP8_MAX_F), FP8_MAX_F);
            q3 = fminf(fmaxf(q3, -FP8_MAX_F), FP8_MAX_F);
            const unsigned int rq = quant4(q0, q1, q2, q3);
            const v2f olo = __builtin_amdgcn_cvt_pk_f32_fp8((int)rq, false);
            const v2f ohi = __builtin_amdgcn_cvt_pk_f32_fp8((int)rq, true);
            *(float4*)(out + (i + j) * 4) = make_float4(olo[0], olo[1], ohi[0], ohi[1]);
        }
    }
}

// --- Fallback kernel (ws too small for q8): recompute from resid_out ---
__global__ __launch_bounds__(256) void k_requant_rows(
    const float* __restrict__ resid_out, const float* __restrict__ w,
    const float* __restrict__ scale_p, const float* __restrict__ inv_arr,
    const float* __restrict__ blockmax, int nblk, float* __restrict__ out)
{
    const int row = blockIdx.x;
    const int t   = threadIdx.x;
    const int lane = t & 63, wid = t >> 6;
    float m = 0.0f;
    for (int i = t * 4; i < nblk; i += 256 * 4) {
        const float4 v = *(const float4*)(blockmax + i);
        m = fmaxf(fmaxf(m, fmaxf(v.x, v.y)), fmaxf(v.z, v.w));
    }
#pragma unroll
    for (int o = 32; o > 0; o >>= 1) m = fmaxf(m, __shfl_down(m, o, 64));
    __shared__ float sm[4];
    if (lane == 0) sm[wid] = m;
    __syncthreads();
    const float amax   = fp8_roundtrip1(fmaxf(fmaxf(sm[0], sm[1]), fmaxf(sm[2], sm[3])));
    const float dscale = fmaxf(amax, 1e-12f) / FP8_MAX_F;

    const size_t base = (size_t)row * H_DIM;
    const float inv = inv_arr[row];
    const float s = scale_p[0];
#pragma unroll
    for (int c = 0; c < 4; ++c) {
        const int col = c * 1024 + t * 4;
        const float4 av = *(const float4*)(resid_out + base + col);
        const float4 wv = *(const float4*)(w + col);
        float qs[4] = { (av.x * inv) * wv.x / s, (av.y * inv) * wv.y / s,
                        (av.z * inv) * wv.z / s, (av.w * inv) * wv.w / s };
        float v[4];
#pragma unroll
        for (int j = 0; j < 4; ++j) {
            float q = fminf(fmaxf(qs[j], -FP8_MAX_F), FP8_MAX_F);
            q = fp8_roundtrip1(q) / dscale;
            q = fminf(fmaxf(q, -FP8_MAX_F), FP8_MAX_F);
            v[j] = fp8_roundtrip1(q);
        }
        *(float4*)(out + base + col) = make_float4(v[0], v[1], v[2], v[3]);
    }
}

// Variant of k1 that also stores per-row inv (fallback mode, no q8 store).
__global__ __launch_bounds__(256) void k_rms_noq(
    const float* __restrict__ hs, const float* __restrict__ res,
    const float* __restrict__ w, const float* __restrict__ scale_p,
    float* __restrict__ resid_out, float* __restrict__ inv_arr,
    float* __restrict__ blockmax)
{
    const int row = blockIdx.x;
    const int t   = threadIdx.x;
    const size_t base = (size_t)row * H_DIM;
    float4 a[4];
    double ss = 0.0;
#pragma unroll
    for (int c = 0; c < 4; ++c) {
        const int col = c * 1024 + t * 4;
        const float4 hv = *(const float4*)(hs + base + col);
        const float4 rv = *(const float4*)(res + base + col);
        float4 av;
        av.x = hv.x + rv.x; av.y = hv.y + rv.y;
        av.z = hv.z + rv.z; av.w = hv.w + rv.w;
        a[c] = av;
        *(float4*)(resid_out + base + col) = av;
        ss += (double)av.x * (double)av.x + (double)av.y * (double)av.y
            + (double)av.z * (double)av.z + (double)av.w * (double)av.w;
    }
    __shared__ double sred[4];
#pragma unroll
    for (int o = 32; o > 0; o >>= 1) ss += __shfl_down(ss, o, 64);
    const int lane = t & 63, wid = t >> 6;
    if (lane == 0) sred[wid] = ss;
    __syncthreads();
    if (t == 0) sred[0] = sred[0] + sred[1] + sred[2] + sred[3];
    __syncthreads();
    const float inv = (float)(1.0 / sqrt(sred[0] / (double)H_DIM + 1e-6));
    if (t == 0) inv_arr[row] = inv;
    const float s = scale_p[0];
    float lmax = 0.0f;
#pragma unroll
    for (int c = 0; c < 4; ++c) {
        const int col = c * 1024 + t * 4;
        const float4 wv = *(const float4*)(w + col);
        const float4 av = a[c];
        float q0 = fminf(fmaxf((av.x * inv) * wv.x / s, -FP8_MAX_F), FP8_MAX_F);
        float q1 = fminf(fmaxf((av.y * inv) * wv.y / s, -FP8_MAX_F), FP8_MAX_F);
        float q2 = fminf(fmaxf((av.z * inv) * wv.z / s, -FP8_MAX_F), FP8_MAX_F);
        float q3 = fminf(fmaxf((av.w * inv) * wv.w / s, -FP8_MAX_F), FP8_MAX_F);
        lmax = fmaxf(lmax, fmaxf(fmaxf(fabsf(q0), fabsf(q1)),
                                 fmaxf(fabsf(q2), fabsf(q3))));
    }
    __shared__ float smax[4];
#pragma unroll
    for (int o = 32; o > 0; o >>= 1) lmax = fmaxf(lmax, __shfl_down(lmax, o, 64));
    if (lane == 0) smax[wid] = lmax;
    __syncthreads();
    if (t == 0)
        blockmax[row] = fmaxf(fmaxf(smax[0], smax[1]), fmaxf(smax[2], smax[3]));
}

extern "C" void kernel_launch(void* const* d_in, const int* in_sizes, int n_in,
                              void* d_out, int out_size, void* d_ws, size_t ws_size,
                              hipStream_t stream) {
    const float* hs    = (const float*)d_in[0];
    const float* res   = (const float*)d_in[1];
    const float* w     = (const float*)d_in[2];
    const float* scale = (const float*)d_in[3];
    const int Hn = in_sizes[2];           // 4096
    const int Tn = in_sizes[0] / Hn;      // 8192
    const size_t nelem  = (size_t)Tn * Hn;
    const size_t nwords = nelem / 4;

    float* q_dyn_out = (float*)d_out;
    float* resid_out = (float*)d_out + nelem;

    // ws layout: [ blockmax: Tn floats ][ inv: Tn floats ][ q8: nelem bytes ]
    float* blockmax = (float*)d_ws;
    float* inv_arr  = (float*)d_ws + Tn;
    unsigned int* q8w = (unsigned int*)((float*)d_ws + 2 * Tn);

    const bool use_q8 = ws_size >= (size_t)2 * Tn * 4 + nelem;

    if (use_q8) {
        k_rms_quant<<<Tn, 256, 0, stream>>>(hs, res, w, scale,
                                            resid_out, q8w, blockmax);
        k_requant<<<2048, 256, 0, stream>>>(q8w, blockmax, Tn, q_dyn_out, nwords);
    } else {
        k_rms_noq<<<Tn, 256, 0, stream>>>(hs, res, w, scale,
                                          resid_out, inv_arr, blockmax);
        k_requant_rows<<<Tn, 256, 0, stream>>>(resid_out, w, scale, inv_arr,
                                               blockmax, Tn, q_dyn_out);
    }
}